// Round 5
// baseline (157.132 us; speedup 1.0000x reference)
//
#include <hip/hip_runtime.h>

// Problem constants (B=4, C_IN=C_OUT=64, H=W=128, K=3, stride=1, pad=1)
// Harness I/O fp32. Internally: NHWC bf16 x, bf16 MFMA for both convs.
#define HW   16384      // H*W
#define NPX  65536      // B*H*W

typedef unsigned short u16;
typedef unsigned int   u32;
typedef short bf16x8 __attribute__((ext_vector_type(8)));   // 8 bf16 = 4 VGPR
typedef float f32x4  __attribute__((ext_vector_type(4)));   // MFMA acc

__device__ __forceinline__ u16 f2b(float f) {               // fp32->bf16 RNE
    u32 u = __float_as_uint(f);
    return (u16)((u + 0x7FFFu + ((u >> 16) & 1u)) >> 16);
}
__device__ __forceinline__ float blo(u32 u) { return __uint_as_float(u << 16); }
__device__ __forceinline__ float bhi(u32 u) { return __uint_as_float(u & 0xffff0000u); }

// XCD-contiguity swizzle (1024-block grids): each XCD owns a contiguous span.
__device__ __forceinline__ int swizzle1024(int bid) {
    return (bid & 7) * 128 + (bid >> 3);
}

// bilinear blend of one u32 (2 bf16 channels) x 4 corners -> packed bf16 pair
__device__ __forceinline__ u32 comb(u32 a00, u32 a01, u32 a10, u32 a11,
                                    float w00, float w01, float w10, float w11) {
    float lo = fmaf(w11, blo(a11), fmaf(w10, blo(a10), fmaf(w01, blo(a01), w00 * blo(a00))));
    float hi = fmaf(w11, bhi(a11), fmaf(w10, bhi(a10), fmaf(w01, bhi(a01), w00 * bhi(a00))));
    return ((__float_as_uint(lo) + 0x8000u) >> 16) | ((__float_as_uint(hi) + 0x8000u) & 0xffff0000u);
}

// 4 corner pointers + 4 bilinear weights for one (px, tap)
struct C4 { const u16 *p00, *p01, *p10, *p11; float w00, w01, w10, w11; };

__device__ __forceinline__ C4 mkc(const u16* xb, float py, float pf) {
    C4 c;
    float y0f = floorf(py), x0f = floorf(pf);
    float wy = py - y0f, wx = pf - x0f;
    int iy0 = (int)y0f, ix0 = (int)x0f;
    // reference semantics: per-corner float-coord validity, clamped gather
    float vy0 = (y0f >=  0.f && y0f <= 127.f) ? 1.f : 0.f;
    float vy1 = (y0f >= -1.f && y0f <= 126.f) ? 1.f : 0.f;
    float vx0 = (x0f >=  0.f && x0f <= 127.f) ? 1.f : 0.f;
    float vx1 = (x0f >= -1.f && x0f <= 126.f) ? 1.f : 0.f;
    int cy0 = min(max(iy0, 0), 127), cy1 = min(max(iy0 + 1, 0), 127);
    int cx0 = min(max(ix0, 0), 127), cx1 = min(max(ix0 + 1, 0), 127);
    c.w00 = (1.f - wy) * (1.f - wx) * vy0 * vx0;
    c.w01 = (1.f - wy) * wx * vy0 * vx1;
    c.w10 = wy * (1.f - wx) * vy1 * vx0;
    c.w11 = wy * wx * vy1 * vx1;
    c.p00 = xb + ((cy0 << 7) + cx0) * 64;
    c.p01 = xb + ((cy0 << 7) + cx1) * 64;
    c.p10 = xb + ((cy1 << 7) + cx0) * 64;
    c.p11 = xb + ((cy1 << 7) + cx1) * 64;
    return c;
}

__device__ __forceinline__ bf16x8 comb4(int4 v00, int4 v01, int4 v10, int4 v11,
                                        const C4& c) {
    int4 r;
    r.x = comb(v00.x, v01.x, v10.x, v11.x, c.w00, c.w01, c.w10, c.w11);
    r.y = comb(v00.y, v01.y, v10.y, v11.y, c.w00, c.w01, c.w10, c.w11);
    r.z = comb(v00.z, v01.z, v10.z, v11.z, c.w00, c.w01, c.w10, c.w11);
    r.w = comb(v00.w, v01.w, v10.w, v11.w, c.w00, c.w01, c.w10, c.w11);
    return __builtin_bit_cast(bf16x8, r);
}

#define MFMA __builtin_amdgcn_mfma_f32_16x16x32_bf16

// ---------------------------------------------------------------------------
// k_pre: x NCHW fp32 -> xh NHWC bf16.  Block = 64 px tile, LDS transpose.
// ---------------------------------------------------------------------------
__global__ __launch_bounds__(256)
void k_pre(const float* __restrict__ x, u16* __restrict__ xh) {
    __shared__ float tile[64][65];
    int tid = threadIdx.x;
    int p0  = swizzle1024(blockIdx.x) * 64;
    int b   = p0 >> 14;
    int hw0 = p0 & (HW - 1);

    int c  = tid >> 2;
    int ch = (tid & 3) * 16;
    const float* src = x + (b * 64 + c) * HW + hw0 + ch;
#pragma unroll
    for (int i = 0; i < 4; ++i) {
        float4 v = *(const float4*)(src + i * 4);
        tile[c][ch + i * 4 + 0] = v.x;
        tile[c][ch + i * 4 + 1] = v.y;
        tile[c][ch + i * 4 + 2] = v.z;
        tile[c][ch + i * 4 + 3] = v.w;
    }
    __syncthreads();

    int px = tid >> 2;
    int cc = (tid & 3) * 16;
    u32 w[8];
#pragma unroll
    for (int i = 0; i < 8; ++i) {
        u32 lo = f2b(tile[cc + 2 * i][px]);
        u32 hi = f2b(tile[cc + 2 * i + 1][px]);
        w[i] = lo | (hi << 16);
    }
    u16* dst = xh + (size_t)(p0 + px) * 64 + cc;
    *(int4*)dst       = make_int4(w[0], w[1], w[2], w[3]);
    *(int4*)(dst + 8) = make_int4(w[4], w[5], w[6], w[7]);
}

// ---------------------------------------------------------------------------
// k_wt: pre-arrange weights into B-fragment-linear bf16.
//   B-frag (16x16x32): lane holds B[k=(lane>>4)*8+j][n=lane&15], j=0..7.
//   wtd: dcn_w,    fid = tap*8 + ks*4 + nt  (72 frags, N=64)
//   wto: offset_w, fid = tap*4 + ks*2 + nt  (36 frags, N=32, n>=18 -> 0)
// ---------------------------------------------------------------------------
__global__ void k_wt(const float* __restrict__ dw, const float* __restrict__ ow,
                     u16* __restrict__ wtd, u16* __restrict__ wto) {
    int gid = blockIdx.x * 256 + threadIdx.x;
    if (gid >= 108 * 64) return;
    int fid = gid >> 6, lane = gid & 63;
    int mi = lane & 15, quad = lane >> 4;
    u32 w[4];
    if (fid < 72) {
        int tap = fid >> 3, rem = fid & 7;
        int ks = rem >> 2, nt = rem & 3;
        int n = nt * 16 + mi;
        int cb = ks * 32 + quad * 8;
#pragma unroll
        for (int i = 0; i < 4; ++i) {
            u32 lo = f2b(dw[(n * 64 + cb + 2 * i) * 9 + tap]);
            u32 hi = f2b(dw[(n * 64 + cb + 2 * i + 1) * 9 + tap]);
            w[i] = lo | (hi << 16);
        }
        *((int4*)wtd + (fid << 6) + lane) = make_int4(w[0], w[1], w[2], w[3]);
    } else {
        int f2 = fid - 72;
        int tap = f2 >> 2, rem = f2 & 3;
        int ks = rem >> 1, nt = rem & 1;
        int n = nt * 16 + mi;
        int cb = ks * 32 + quad * 8;
#pragma unroll
        for (int i = 0; i < 4; ++i) {
            u32 lo = (n < 18) ? f2b(ow[(n * 64 + cb + 2 * i) * 9 + tap]) : 0u;
            u32 hi = (n < 18) ? f2b(ow[(n * 64 + cb + 2 * i + 1) * 9 + tap]) : 0u;
            w[i] = lo | (hi << 16);
        }
        *((int4*)wto + (f2 << 6) + lane) = make_int4(w[0], w[1], w[2], w[3]);
    }
}

// ---------------------------------------------------------------------------
// k_main: FUSED offset conv + deformable conv.  Block = 64 px, 4 waves,
// wave = 16 px x full N.  Phase 1: offset conv via MFMA (branchless),
// offsets -> LDS.  Phase 2: per-lane register gather/blend -> bf16 A-frag,
// half-tap software pipeline (corner + B-frag prefetch one stage ahead).
// Epilogue: LDS transpose -> coalesced stores + BN partial atomics.
// ---------------------------------------------------------------------------
__global__ __launch_bounds__(256, 4)
void k_main(const u16* __restrict__ xh, const u16* __restrict__ wto,
            const u16* __restrict__ wtd, const float* __restrict__ ob,
            float* __restrict__ out, float* __restrict__ sums) {
    __shared__ float offs[18][66];
    __shared__ float so[64][65];

    int tid = threadIdx.x;
    int p0  = swizzle1024(blockIdx.x) * 64;
    int b   = p0 >> 14;
    int hw0 = p0 & (HW - 1);
    int y   = hw0 >> 7;
    int x0  = hw0 & 127;
    int wave = tid >> 6, lane = tid & 63;
    int mi = lane & 15, quad = lane >> 4;
    int m0 = wave << 4;
    int xcol = x0 + m0 + mi;
    int koff = quad * 8;                    // u16 offset for ks=0 channels
    const u16* xb = xh + (size_t)b * HW * 64;
    const bf16x8* WO = (const bf16x8*)wto;
    const bf16x8* WD = (const bf16x8*)wtd;

    // ---- phase 1: offset conv (fixed taps, branchless boundary) ----
    f32x4 oa0 = {0.f, 0.f, 0.f, 0.f}, oa1 = {0.f, 0.f, 0.f, 0.f};
#pragma unroll
    for (int tap = 0; tap < 9; ++tap) {
        int yy = y + tap / 3 - 1;
        int xx = xcol + tap % 3 - 1;
        int yc = min(max(yy, 0), 127), xc = min(max(xx, 0), 127);
        bool valid = ((unsigned)yy < 128u) && ((unsigned)xx < 128u);
        const u16* ap = xb + ((yc << 7) + xc) * 64 + koff;
        int4 a0 = *(const int4*)ap;
        int4 a1 = *(const int4*)(ap + 32);
        if (!valid) { a0 = make_int4(0, 0, 0, 0); a1 = make_int4(0, 0, 0, 0); }
        bf16x8 f0 = __builtin_bit_cast(bf16x8, a0);
        bf16x8 f1 = __builtin_bit_cast(bf16x8, a1);
        oa0 = MFMA(f0, WO[((tap * 4 + 0) << 6) + lane], oa0, 0, 0, 0);
        oa1 = MFMA(f0, WO[((tap * 4 + 1) << 6) + lane], oa1, 0, 0, 0);
        oa0 = MFMA(f1, WO[((tap * 4 + 2) << 6) + lane], oa0, 0, 0, 0);
        oa1 = MFMA(f1, WO[((tap * 4 + 3) << 6) + lane], oa1, 0, 0, 0);
    }
    // C layout: col = lane&15 = n, row = quad*4+r = px-in-wave-tile
    {
        float bias = ob[mi];                           // n = mi (0..15)
#pragma unroll
        for (int r = 0; r < 4; ++r)
            offs[mi][m0 + quad * 4 + r] = oa0[r] + bias;
        if (mi < 2) {                                  // n = 16+mi (16..17)
            float bias1 = ob[16 + mi];
#pragma unroll
            for (int r = 0; r < 4; ++r)
                offs[16 + mi][m0 + quad * 4 + r] = oa1[r] + bias1;
        }
    }
    __syncthreads();

    // ---- phase 2: deformable conv, half-tap software pipeline ----
    f32x4 acc0 = {0.f,0.f,0.f,0.f}, acc1 = {0.f,0.f,0.f,0.f};
    f32x4 acc2 = {0.f,0.f,0.f,0.f}, acc3 = {0.f,0.f,0.f,0.f};
    float fy = (float)y, fx = (float)xcol;
    int pxl = m0 + mi;                                  // this lane's px slot

    C4 cur = mkc(xb, offs[0][pxl] + (fy - 1.f), offs[1][pxl] + (fx - 1.f));
    int4 c00 = *(const int4*)(cur.p00 + koff);
    int4 c01 = *(const int4*)(cur.p01 + koff);
    int4 c10 = *(const int4*)(cur.p10 + koff);
    int4 c11 = *(const int4*)(cur.p11 + koff);
    bf16x8 b0 = WD[(0 << 6) + lane], b1 = WD[(1 << 6) + lane];
    bf16x8 b2 = WD[(2 << 6) + lane], b3 = WD[(3 << 6) + lane];

#pragma unroll
    for (int tap = 0; tap < 9; ++tap) {
        // prefetch stage (tap, ks=1): corners at +32 ch, B frags 4..7
        int4 d00 = *(const int4*)(cur.p00 + koff + 32);
        int4 d01 = *(const int4*)(cur.p01 + koff + 32);
        int4 d10 = *(const int4*)(cur.p10 + koff + 32);
        int4 d11 = *(const int4*)(cur.p11 + koff + 32);
        bf16x8 n0 = WD[((tap * 8 + 4) << 6) + lane];
        bf16x8 n1 = WD[((tap * 8 + 5) << 6) + lane];
        bf16x8 n2 = WD[((tap * 8 + 6) << 6) + lane];
        bf16x8 n3 = WD[((tap * 8 + 7) << 6) + lane];

        bf16x8 a = comb4(c00, c01, c10, c11, cur);
        acc0 = MFMA(a, b0, acc0, 0, 0, 0);
        acc1 = MFMA(a, b1, acc1, 0, 0, 0);
        acc2 = MFMA(a, b2, acc2, 0, 0, 0);
        acc3 = MFMA(a, b3, acc3, 0, 0, 0);

        // prefetch stage (tap+1, ks=0)
        C4 nxt = cur;
        if (tap < 8) {
            int t = tap + 1;
            nxt = mkc(xb, offs[2 * t][pxl] + (fy + (float)(t / 3 - 1)),
                          offs[2 * t + 1][pxl] + (fx + (float)(t % 3 - 1)));
            c00 = *(const int4*)(nxt.p00 + koff);
            c01 = *(const int4*)(nxt.p01 + koff);
            c10 = *(const int4*)(nxt.p10 + koff);
            c11 = *(const int4*)(nxt.p11 + koff);
            b0 = WD[((t * 8 + 0) << 6) + lane];
            b1 = WD[((t * 8 + 1) << 6) + lane];
            b2 = WD[((t * 8 + 2) << 6) + lane];
            b3 = WD[((t * 8 + 3) << 6) + lane];
        }

        bf16x8 a2 = comb4(d00, d01, d10, d11, cur);   // cur still holds tap's wts
        acc0 = MFMA(a2, n0, acc0, 0, 0, 0);
        acc1 = MFMA(a2, n1, acc1, 0, 0, 0);
        acc2 = MFMA(a2, n2, acc2, 0, 0, 0);
        acc3 = MFMA(a2, n3, acc3, 0, 0, 0);
        cur = nxt;
    }

    // ---- epilogue: transpose via LDS, coalesced stores, BN partials ----
#pragma unroll
    for (int r = 0; r < 4; ++r) {
        so[ 0 + mi][m0 + quad * 4 + r] = acc0[r];
        so[16 + mi][m0 + quad * 4 + r] = acc1[r];
        so[32 + mi][m0 + quad * 4 + r] = acc2[r];
        so[48 + mi][m0 + quad * 4 + r] = acc3[r];
    }
    __syncthreads();

    int n  = tid >> 2;
    int c4 = tid & 3;
    int pl = c4 * 16;
    float s = 0.f, q = 0.f;
    float vals[16];
#pragma unroll
    for (int i = 0; i < 16; ++i) {
        float v = so[n][pl + i];
        vals[i] = v;
        s += v;
        q = fmaf(v, v, q);
    }
    float* dst = out + ((b * 64 + n) * HW) + (y << 7) + x0 + pl;
#pragma unroll
    for (int i = 0; i < 4; ++i)
        *(float4*)(dst + i * 4) =
            make_float4(vals[4*i], vals[4*i+1], vals[4*i+2], vals[4*i+3]);

    s += __shfl_xor(s, 1); s += __shfl_xor(s, 2);
    q += __shfl_xor(q, 1); q += __shfl_xor(q, 2);
    if (c4 == 0) {
        atomicAdd(&sums[n], s);
        atomicAdd(&sums[64 + n], q);
    }
}

// ---------------------------------------------------------------------------
// k_bn: BN (biased var) + gamma/beta + ReLU, in place over d_out.
// ---------------------------------------------------------------------------
__global__ __launch_bounds__(256)
void k_bn(float* __restrict__ out, const float* __restrict__ sums,
          const float* __restrict__ gamma, const float* __restrict__ beta) {
    int i4 = blockIdx.x * 256 + threadIdx.x;
    int e  = i4 << 2;
    int o  = (e >> 14) & 63;
    const float n = 65536.f;
    float mean = sums[o] / n;
    float var  = fmaxf(sums[64 + o] / n - mean * mean, 0.f);
    float sc   = rsqrtf(var + 1e-5f) * gamma[o];
    float sh   = beta[o] - mean * sc;
    float4 v = *(const float4*)&out[e];
    v.x = fmaxf(fmaf(v.x, sc, sh), 0.f);
    v.y = fmaxf(fmaf(v.y, sc, sh), 0.f);
    v.z = fmaxf(fmaf(v.z, sc, sh), 0.f);
    v.w = fmaxf(fmaf(v.w, sc, sh), 0.f);
    *(float4*)&out[e] = v;
}

// ---------------------------------------------------------------------------
// Workspace layout (bytes):
//   xh   : [0, 8388608)            NHWC bf16 x
//   wtd  : [8388608, 8462336)      72 B-frags dcn weights
//   wto  : [8462336, 8499200)      36 B-frags offset weights
//   sums : [8499200, 8499712)      BN partials (zeroed per call)
// ---------------------------------------------------------------------------
extern "C" void kernel_launch(void* const* d_in, const int* in_sizes, int n_in,
                              void* d_out, int out_size, void* d_ws, size_t ws_size,
                              hipStream_t stream) {
    const float* x     = (const float*)d_in[0];
    const float* ow    = (const float*)d_in[1];
    const float* ob    = (const float*)d_in[2];
    const float* dw    = (const float*)d_in[3];
    const float* gamma = (const float*)d_in[4];
    const float* beta  = (const float*)d_in[5];
    float* out = (float*)d_out;
    char*  wsb = (char*)d_ws;
    u16*   xh   = (u16*)wsb;
    u16*   wtd  = (u16*)(wsb + 8388608);
    u16*   wto  = (u16*)(wsb + 8462336);
    float* sums = (float*)(wsb + 8499200);

    hipMemsetAsync(sums, 0, 128 * sizeof(float), stream);
    k_pre<<<1024, 256, 0, stream>>>(x, xh);
    k_wt<<<27, 256, 0, stream>>>(dw, ow, wtd, wto);
    k_main<<<1024, 256, 0, stream>>>(xh, wto, wtd, ob, out, sums);
    k_bn<<<4096, 256, 0, stream>>>(out, sums, gamma, beta);
}

// Round 6
// 143.001 us; speedup vs baseline: 1.0988x; 1.0988x over previous
//
#include <hip/hip_runtime.h>

// Problem constants (B=4, C_IN=C_OUT=64, H=W=128, K=3, stride=1, pad=1)
// Harness I/O fp32. Internally: NHWC bf16 x, bf16 MFMA for both convs.
#define HW   16384      // H*W
#define NPX  65536      // B*H*W

typedef unsigned short u16;
typedef unsigned int   u32;
typedef short bf16x8 __attribute__((ext_vector_type(8)));   // 8 bf16 = 4 VGPR
typedef float f32x4  __attribute__((ext_vector_type(4)));   // MFMA acc

__device__ __forceinline__ u16 f2b(float f) {               // fp32->bf16 RNE
    u32 u = __float_as_uint(f);
    return (u16)((u + 0x7FFFu + ((u >> 16) & 1u)) >> 16);
}
__device__ __forceinline__ float blo(u32 u) { return __uint_as_float(u << 16); }
__device__ __forceinline__ float bhi(u32 u) { return __uint_as_float(u & 0xffff0000u); }

// bilinear blend of one u32 (2 bf16 channels) x 4 corners -> packed bf16 pair
__device__ __forceinline__ u32 comb(u32 a00, u32 a01, u32 a10, u32 a11,
                                    float w00, float w01, float w10, float w11) {
    float lo = fmaf(w11, blo(a11), fmaf(w10, blo(a10), fmaf(w01, blo(a01), w00 * blo(a00))));
    float hi = fmaf(w11, bhi(a11), fmaf(w10, bhi(a10), fmaf(w01, bhi(a01), w00 * bhi(a00))));
    return ((__float_as_uint(lo) + 0x8000u) >> 16) | ((__float_as_uint(hi) + 0x8000u) & 0xffff0000u);
}

#define MFMA __builtin_amdgcn_mfma_f32_16x16x32_bf16

// ---------------------------------------------------------------------------
// k_pre: blocks [0,1024): x NCHW fp32 -> xh NHWC bf16 (contiguous-per-group
// loads: 4 lanes cover 64B per instr). Blocks [1024,1051): weight prep into
// B-fragment-linear bf16 (frag: lane holds B[k=(lane>>4)*8+j][n=lane&15]).
//   wtd: dcn_w,    fid = tap*8 + ks*4 + nt  (72 frags, N=64)
//   wto: offset_w, fid = tap*4 + ks*2 + nt  (36 frags, N=32, n>=18 -> 0)
// ---------------------------------------------------------------------------
__global__ __launch_bounds__(256)
void k_pre(const float* __restrict__ x, const float* __restrict__ dw,
           const float* __restrict__ ow, u16* __restrict__ xh,
           u16* __restrict__ wtd, u16* __restrict__ wto) {
    int tid = threadIdx.x;
    if (blockIdx.x >= 1024) {               // ---- weight prep ----
        int gid = (blockIdx.x - 1024) * 256 + tid;
        if (gid >= 108 * 64) return;
        int fid = gid >> 6, lane = gid & 63;
        int mi = lane & 15, quad = lane >> 4;
        u32 w[4];
        if (fid < 72) {
            int tap = fid >> 3, rem = fid & 7;
            int ks = rem >> 2, nt = rem & 3;
            int n = nt * 16 + mi;
            int cb = ks * 32 + quad * 8;
#pragma unroll
            for (int i = 0; i < 4; ++i) {
                u32 lo = f2b(dw[(n * 64 + cb + 2 * i) * 9 + tap]);
                u32 hi = f2b(dw[(n * 64 + cb + 2 * i + 1) * 9 + tap]);
                w[i] = lo | (hi << 16);
            }
            *((int4*)wtd + (fid << 6) + lane) = make_int4(w[0], w[1], w[2], w[3]);
        } else {
            int f2 = fid - 72;
            int tap = f2 >> 2, rem = f2 & 3;
            int ks = rem >> 1, nt = rem & 1;
            int n = nt * 16 + mi;
            int cb = ks * 32 + quad * 8;
#pragma unroll
            for (int i = 0; i < 4; ++i) {
                u32 lo = (n < 18) ? f2b(ow[(n * 64 + cb + 2 * i) * 9 + tap]) : 0u;
                u32 hi = (n < 18) ? f2b(ow[(n * 64 + cb + 2 * i + 1) * 9 + tap]) : 0u;
                w[i] = lo | (hi << 16);
            }
            *((int4*)wto + (f2 << 6) + lane) = make_int4(w[0], w[1], w[2], w[3]);
        }
        return;
    }
    // ---- NCHW fp32 -> NHWC bf16 ----
    __shared__ float tile[64][65];
    int p0  = blockIdx.x * 64;
    int b   = p0 >> 14;
    int hw0 = p0 & (HW - 1);
    int c   = tid >> 2;
    int sub = tid & 3;
    const float* src = x + (size_t)(b * 64 + c) * HW + hw0;
#pragma unroll
    for (int i = 0; i < 4; ++i) {           // lanes 0-3 cover 64B contiguous
        float4 v = *(const float4*)(src + i * 16 + sub * 4);
        tile[c][i * 16 + sub * 4 + 0] = v.x;
        tile[c][i * 16 + sub * 4 + 1] = v.y;
        tile[c][i * 16 + sub * 4 + 2] = v.z;
        tile[c][i * 16 + sub * 4 + 3] = v.w;
    }
    __syncthreads();

    int px = tid >> 2;
    u32 w1[4], w2[4];
#pragma unroll
    for (int j = 0; j < 4; ++j) {
        int ch = sub * 8 + 2 * j;
        w1[j] = (u32)f2b(tile[ch][px])      | ((u32)f2b(tile[ch + 1][px]) << 16);
        w2[j] = (u32)f2b(tile[ch + 32][px]) | ((u32)f2b(tile[ch + 33][px]) << 16);
    }
    u16* dst = xh + (size_t)(p0 + px) * 64;
    *(int4*)(dst + sub * 8)      = make_int4(w1[0], w1[1], w1[2], w1[3]);
    *(int4*)(dst + 32 + sub * 8) = make_int4(w2[0], w2[1], w2[2], w2[3]);
}

// ---------------------------------------------------------------------------
// k_main: FUSED offset conv + deformable conv, ks-SPLIT for 2x waves.
// 2048 blocks x 256 thr; block = 32 px (one row segment).  Wave layout:
// wave = (ks, px-half); each wave = 16 px x 64 out x 32 channels (K=288).
// Phase 1: offset conv partials via MFMA -> offs[ks] LDS planes.
// Phase 2: per-lane register gather/blend -> bf16 A-frag -> 4 MFMA per tap.
// Epilogue: ks1 writes so, ks0 adds, then coalesced stores + XCD-binned
// BN partial atomics.
// ---------------------------------------------------------------------------
__global__ __launch_bounds__(256, 6)
void k_main(const u16* __restrict__ xh, const u16* __restrict__ wto,
            const u16* __restrict__ wtd, const float* __restrict__ ob,
            float* __restrict__ out, float* __restrict__ sums) {
    __shared__ float offs[2][18][34];
    __shared__ float so[64][33];

    int tid = threadIdx.x;
    int vb  = (blockIdx.x & 7) * 256 + (blockIdx.x >> 3);   // XCD-contig
    int p0  = vb * 32;
    int b   = p0 >> 14;
    int hw0 = p0 & (HW - 1);
    int y   = hw0 >> 7;
    int x0  = hw0 & 127;
    int wave = tid >> 6, lane = tid & 63;
    int mi = lane & 15, quad = lane >> 4;
    int ks = wave >> 1;
    int m0 = (wave & 1) << 4;
    int xcol = x0 + m0 + mi;
    int koff = ks * 32 + quad * 8;          // u16 offset: this wave's 8 ch
    const u16* xb = xh + (size_t)b * HW * 64;
    const bf16x8* WO = (const bf16x8*)wto;
    const bf16x8* WD = (const bf16x8*)wtd;

    // ---- phase 1: offset conv partial (this ks half) ----
    f32x4 oa0 = {0.f, 0.f, 0.f, 0.f}, oa1 = {0.f, 0.f, 0.f, 0.f};
#pragma unroll
    for (int tap = 0; tap < 9; ++tap) {
        int yy = y + tap / 3 - 1;
        int xx = xcol + tap % 3 - 1;
        int yc = min(max(yy, 0), 127), xc = min(max(xx, 0), 127);
        bool valid = ((unsigned)yy < 128u) && ((unsigned)xx < 128u);
        int4 a = *(const int4*)(xb + ((yc << 7) + xc) * 64 + koff);
        if (!valid) a = make_int4(0, 0, 0, 0);
        bf16x8 af = __builtin_bit_cast(bf16x8, a);
        oa0 = MFMA(af, WO[((tap * 4 + ks * 2 + 0) << 6) + lane], oa0, 0, 0, 0);
        oa1 = MFMA(af, WO[((tap * 4 + ks * 2 + 1) << 6) + lane], oa1, 0, 0, 0);
    }
    {   // C layout: col = lane&15 = n, row = quad*4+r = px-in-wave-tile
        float bias0 = (ks == 0) ? ob[mi] : 0.f;
#pragma unroll
        for (int r = 0; r < 4; ++r)
            offs[ks][mi][m0 + quad * 4 + r] = oa0[r] + bias0;
        if (mi < 2) {
            float bias1 = (ks == 0) ? ob[16 + mi] : 0.f;
#pragma unroll
            for (int r = 0; r < 4; ++r)
                offs[ks][16 + mi][m0 + quad * 4 + r] = oa1[r] + bias1;
        }
    }
    __syncthreads();

    // ---- phase 2: deformable conv (this ks half) ----
    f32x4 acc0 = {0.f,0.f,0.f,0.f}, acc1 = {0.f,0.f,0.f,0.f};
    f32x4 acc2 = {0.f,0.f,0.f,0.f}, acc3 = {0.f,0.f,0.f,0.f};
    int   pxl = m0 + mi;
    float fy = (float)y, fx = (float)xcol;
#pragma unroll
    for (int tap = 0; tap < 9; ++tap) {
        float dy = offs[0][2 * tap][pxl]     + offs[1][2 * tap][pxl];
        float dx = offs[0][2 * tap + 1][pxl] + offs[1][2 * tap + 1][pxl];
        // reference semantics: per-corner float-coord validity, clamped gather
        float py  = dy + fy + (float)(tap / 3 - 1);
        float pf  = dx + fx + (float)(tap % 3 - 1);
        float y0f = floorf(py), x0f = floorf(pf);
        float wy  = py - y0f,   wx  = pf - x0f;
        int   iy0 = (int)y0f,   ix0 = (int)x0f;
        float vy0 = (y0f >=  0.f && y0f <= 127.f) ? 1.f : 0.f;
        float vy1 = (y0f >= -1.f && y0f <= 126.f) ? 1.f : 0.f;
        float vx0 = (x0f >=  0.f && x0f <= 127.f) ? 1.f : 0.f;
        float vx1 = (x0f >= -1.f && x0f <= 126.f) ? 1.f : 0.f;
        int cy0 = min(max(iy0, 0), 127), cy1 = min(max(iy0 + 1, 0), 127);
        int cx0 = min(max(ix0, 0), 127), cx1 = min(max(ix0 + 1, 0), 127);
        float w00 = (1.f - wy) * (1.f - wx) * vy0 * vx0;
        float w01 = (1.f - wy) * wx * vy0 * vx1;
        float w10 = wy * (1.f - wx) * vy1 * vx0;
        float w11 = wy * wx * vy1 * vx1;
        int4 v00 = *(const int4*)(xb + ((cy0 << 7) + cx0) * 64 + koff);
        int4 v01 = *(const int4*)(xb + ((cy0 << 7) + cx1) * 64 + koff);
        int4 v10 = *(const int4*)(xb + ((cy1 << 7) + cx0) * 64 + koff);
        int4 v11 = *(const int4*)(xb + ((cy1 << 7) + cx1) * 64 + koff);
        int4 r;
        r.x = comb(v00.x, v01.x, v10.x, v11.x, w00, w01, w10, w11);
        r.y = comb(v00.y, v01.y, v10.y, v11.y, w00, w01, w10, w11);
        r.z = comb(v00.z, v01.z, v10.z, v11.z, w00, w01, w10, w11);
        r.w = comb(v00.w, v01.w, v10.w, v11.w, w00, w01, w10, w11);
        bf16x8 a = __builtin_bit_cast(bf16x8, r);
        acc0 = MFMA(a, WD[((tap * 8 + ks * 4 + 0) << 6) + lane], acc0, 0, 0, 0);
        acc1 = MFMA(a, WD[((tap * 8 + ks * 4 + 1) << 6) + lane], acc1, 0, 0, 0);
        acc2 = MFMA(a, WD[((tap * 8 + ks * 4 + 2) << 6) + lane], acc2, 0, 0, 0);
        acc3 = MFMA(a, WD[((tap * 8 + ks * 4 + 3) << 6) + lane], acc3, 0, 0, 0);
    }

    // ---- epilogue: combine ks halves in LDS, store, BN partials ----
    if (ks == 1) {
#pragma unroll
        for (int r = 0; r < 4; ++r) {
            so[ 0 + mi][m0 + quad * 4 + r] = acc0[r];
            so[16 + mi][m0 + quad * 4 + r] = acc1[r];
            so[32 + mi][m0 + quad * 4 + r] = acc2[r];
            so[48 + mi][m0 + quad * 4 + r] = acc3[r];
        }
    }
    __syncthreads();
    if (ks == 0) {
#pragma unroll
        for (int r = 0; r < 4; ++r) {
            so[ 0 + mi][m0 + quad * 4 + r] += acc0[r];
            so[16 + mi][m0 + quad * 4 + r] += acc1[r];
            so[32 + mi][m0 + quad * 4 + r] += acc2[r];
            so[48 + mi][m0 + quad * 4 + r] += acc3[r];
        }
    }
    __syncthreads();

    int n  = tid >> 2;
    int c4 = tid & 3;
    int pl = c4 * 8;
    float s = 0.f, q = 0.f;
    float vals[8];
#pragma unroll
    for (int i = 0; i < 8; ++i) {
        float v = so[n][pl + i];
        vals[i] = v;
        s += v;
        q = fmaf(v, v, q);
    }
    float* dst = out + (size_t)(b * 64 + n) * HW + (y << 7) + x0 + pl;
    *(float4*)dst       = make_float4(vals[0], vals[1], vals[2], vals[3]);
    *(float4*)(dst + 4) = make_float4(vals[4], vals[5], vals[6], vals[7]);

    s += __shfl_xor(s, 1); s += __shfl_xor(s, 2);
    q += __shfl_xor(q, 1); q += __shfl_xor(q, 2);
    if (c4 == 0) {                          // per-XCD bin: 8x less contention
        float* sb = sums + (blockIdx.x & 7) * 128;
        atomicAdd(&sb[n], s);
        atomicAdd(&sb[64 + n], q);
    }
}

// ---------------------------------------------------------------------------
// k_bn: BN (biased var) + gamma/beta + ReLU, in place over d_out.
// sums has 8 per-XCD bins of [64 sum | 64 sumsq].
// ---------------------------------------------------------------------------
__global__ __launch_bounds__(256)
void k_bn(float* __restrict__ out, const float* __restrict__ sums,
          const float* __restrict__ gamma, const float* __restrict__ beta) {
    int i4 = blockIdx.x * 256 + threadIdx.x;
    int e  = i4 << 2;
    int o  = (e >> 14) & 63;
    float sm = 0.f, sq = 0.f;
#pragma unroll
    for (int s8 = 0; s8 < 8; ++s8) {
        sm += sums[s8 * 128 + o];
        sq += sums[s8 * 128 + 64 + o];
    }
    const float n = 65536.f;
    float mean = sm / n;
    float var  = fmaxf(sq / n - mean * mean, 0.f);
    float sc   = rsqrtf(var + 1e-5f) * gamma[o];
    float sh   = beta[o] - mean * sc;
    float4 v = *(const float4*)&out[e];
    v.x = fmaxf(fmaf(v.x, sc, sh), 0.f);
    v.y = fmaxf(fmaf(v.y, sc, sh), 0.f);
    v.z = fmaxf(fmaf(v.z, sc, sh), 0.f);
    v.w = fmaxf(fmaf(v.w, sc, sh), 0.f);
    *(float4*)&out[e] = v;
}

// ---------------------------------------------------------------------------
// Workspace layout (bytes):
//   xh   : [0, 8388608)            NHWC bf16 x
//   wtd  : [8388608, 8462336)      72 B-frags dcn weights
//   wto  : [8462336, 8499200)      36 B-frags offset weights
//   sums : [8499200, 8503296)      BN partials, 8 XCD bins (zeroed per call)
// ---------------------------------------------------------------------------
extern "C" void kernel_launch(void* const* d_in, const int* in_sizes, int n_in,
                              void* d_out, int out_size, void* d_ws, size_t ws_size,
                              hipStream_t stream) {
    const float* x     = (const float*)d_in[0];
    const float* ow    = (const float*)d_in[1];
    const float* ob    = (const float*)d_in[2];
    const float* dw    = (const float*)d_in[3];
    const float* gamma = (const float*)d_in[4];
    const float* beta  = (const float*)d_in[5];
    float* out = (float*)d_out;
    char*  wsb = (char*)d_ws;
    u16*   xh   = (u16*)wsb;
    u16*   wtd  = (u16*)(wsb + 8388608);
    u16*   wto  = (u16*)(wsb + 8462336);
    float* sums = (float*)(wsb + 8499200);

    hipMemsetAsync(sums, 0, 8 * 128 * sizeof(float), stream);
    k_pre<<<1051, 256, 0, stream>>>(x, dw, ow, xh, wtd, wto);
    k_main<<<2048, 256, 0, stream>>>(xh, wto, wtd, ob, out, sums);
    k_bn<<<4096, 256, 0, stream>>>(out, sums, gamma, beta);
}

// Round 8
// 142.268 us; speedup vs baseline: 1.1045x; 1.0051x over previous
//
#include <hip/hip_runtime.h>

// Problem constants (B=4, C_IN=C_OUT=64, H=W=128, K=3, stride=1, pad=1)
// Harness I/O fp32. Internally: NHWC bf16 x, bf16 MFMA for both convs.
#define HW   16384
#define NPX  65536

typedef unsigned short u16;
typedef unsigned int   u32;
typedef short bf16x8 __attribute__((ext_vector_type(8)));
typedef float f32x4  __attribute__((ext_vector_type(4)));

__device__ __forceinline__ u16 f2b(float f) {               // fp32->bf16 RNE
    u32 u = __float_as_uint(f);
    return (u16)((u + 0x7FFFu + ((u >> 16) & 1u)) >> 16);
}
__device__ __forceinline__ float blo(u32 u) { return __uint_as_float(u << 16); }
__device__ __forceinline__ float bhi(u32 u) { return __uint_as_float(u & 0xffff0000u); }

// bilinear blend of one u32 (2 bf16 channels) x 4 corners -> packed bf16 pair
__device__ __forceinline__ u32 comb(u32 a00, u32 a01, u32 a10, u32 a11,
                                    float w00, float w01, float w10, float w11) {
    float lo = fmaf(w11, blo(a11), fmaf(w10, blo(a10), fmaf(w01, blo(a01), w00 * blo(a00))));
    float hi = fmaf(w11, bhi(a11), fmaf(w10, bhi(a10), fmaf(w01, bhi(a01), w00 * bhi(a00))));
    return ((__float_as_uint(lo) + 0x8000u) >> 16) | ((__float_as_uint(hi) + 0x8000u) & 0xffff0000u);
}
__device__ __forceinline__ bf16x8 comb4(int4 v00, int4 v01, int4 v10, int4 v11,
                                        float w00, float w01, float w10, float w11) {
    int4 r;
    r.x = comb(v00.x, v01.x, v10.x, v11.x, w00, w01, w10, w11);
    r.y = comb(v00.y, v01.y, v10.y, v11.y, w00, w01, w10, w11);
    r.z = comb(v00.z, v01.z, v10.z, v11.z, w00, w01, w10, w11);
    r.w = comb(v00.w, v01.w, v10.w, v11.w, w00, w01, w10, w11);
    return __builtin_bit_cast(bf16x8, r);
}

#define MFMA __builtin_amdgcn_mfma_f32_16x16x32_bf16

// ---------------------------------------------------------------------------
// k_pre: blocks [0,512): NCHW fp32 -> NHWC bf16, 128-px tiles.
//   Load side fully coalesced: half-wave reads 512B contiguous of one row,
//   8 rows per iteration.  Transpose via u16 LDS tile (stride 138: the
//   16-channel column readers land on 2 banks -> 2-way, free).
// Blocks [512,539): weight prep to B-frag-linear bf16
//   (frag: lane holds B[k=(lane>>4)*8+j][n=lane&15], j=0..7).
//   wtd: dcn_w,    fid = tap*8 + ks*4 + nt  (72 frags, N=64)
//   wto: offset_w, fid = tap*4 + ks*2 + nt  (36 frags, N=32, n>=18 -> 0)
// Block 539: zero BN partial bins (replaces hipMemsetAsync node).
// ---------------------------------------------------------------------------
__global__ __launch_bounds__(256)
void k_pre(const float* __restrict__ x, const float* __restrict__ dw,
           const float* __restrict__ ow, u16* __restrict__ xh,
           u16* __restrict__ wtd, u16* __restrict__ wto,
           float* __restrict__ sums) {
    int tid = threadIdx.x;
    int bid = blockIdx.x;
    if (bid >= 512) {
        if (bid == 539) {
            for (int i = tid; i < 1024; i += 256) sums[i] = 0.f;
            return;
        }
        int gid = (bid - 512) * 256 + tid;       // ---- weight prep ----
        if (gid >= 108 * 64) return;
        int fid = gid >> 6, lane = gid & 63;
        int mi = lane & 15, quad = lane >> 4;
        u32 w[4];
        if (fid < 72) {
            int tap = fid >> 3, rem = fid & 7;
            int ks = rem >> 2, nt = rem & 3;
            int n = nt * 16 + mi;
            int cb = ks * 32 + quad * 8;
#pragma unroll
            for (int i = 0; i < 4; ++i) {
                u32 lo = f2b(dw[(n * 64 + cb + 2 * i) * 9 + tap]);
                u32 hi = f2b(dw[(n * 64 + cb + 2 * i + 1) * 9 + tap]);
                w[i] = lo | (hi << 16);
            }
            *((int4*)wtd + (fid << 6) + lane) = make_int4(w[0], w[1], w[2], w[3]);
        } else {
            int f2 = fid - 72;
            int tap = f2 >> 2, rem = f2 & 3;
            int ks = rem >> 1, nt = rem & 1;
            int n = nt * 16 + mi;
            int cb = ks * 32 + quad * 8;
#pragma unroll
            for (int i = 0; i < 4; ++i) {
                u32 lo = (n < 18) ? f2b(ow[(n * 64 + cb + 2 * i) * 9 + tap]) : 0u;
                u32 hi = (n < 18) ? f2b(ow[(n * 64 + cb + 2 * i + 1) * 9 + tap]) : 0u;
                w[i] = lo | (hi << 16);
            }
            *((int4*)wto + (f2 << 6) + lane) = make_int4(w[0], w[1], w[2], w[3]);
        }
        return;
    }
    // ---- NCHW fp32 -> NHWC bf16, 128-px tile ----
    __shared__ u16 tile[64][138];
    int p0  = bid * 128;
    int b   = p0 >> 14;
    int hw0 = p0 & (HW - 1);
    int pxq = (tid & 31) * 4;
    int rr  = tid >> 5;                          // 0..7
    const float* src = x + (size_t)b * 64 * HW + hw0 + pxq;
#pragma unroll
    for (int i = 0; i < 8; ++i) {
        int c = i * 8 + rr;
        float4 v = *(const float4*)(src + (size_t)c * HW);
        ushort4 h;
        h.x = f2b(v.x); h.y = f2b(v.y); h.z = f2b(v.z); h.w = f2b(v.w);
        *(ushort4*)&tile[c][pxq] = h;
    }
    __syncthreads();
    int sub = tid & 3;
#pragma unroll
    for (int j = 0; j < 2; ++j) {
        int px = j * 64 + (tid >> 2);
        u32 w[8];
#pragma unroll
        for (int t = 0; t < 8; ++t) {
            int c = sub * 16 + 2 * t;
            w[t] = (u32)tile[c][px] | ((u32)tile[c + 1][px] << 16);
        }
        u16* dst = xh + (size_t)(p0 + px) * 64 + sub * 16;
        *(int4*)dst       = make_int4(w[0], w[1], w[2], w[3]);
        *(int4*)(dst + 8) = make_int4(w[4], w[5], w[6], w[7]);
    }
}

// ---------------------------------------------------------------------------
// k_main: FUSED offset conv + deformable conv, ks-split, depth-2 pipeline.
// 2048 blocks x 256 thr; block = 32 px.  Wave = (ks, px-half): 16 px x 64
// out x 32 ch (K=288).  Phase 1: offset conv partials (9 loads upfront) ->
// offs LDS.  Phase 2: per-tap register gather/blend -> bf16 A-frag -> 4
// MFMA; next tap's 4 corner loads + 4 B-frags pinned ABOVE current compute
// via sched_barrier(0) so the compiler cannot re-serialize the chain.
// Epilogue: combine ks halves in LDS, coalesced stores, XCD-binned atomics.
// ---------------------------------------------------------------------------
__global__ __launch_bounds__(256, 4)
void k_main(const u16* __restrict__ xh, const u16* __restrict__ wto,
            const u16* __restrict__ wtd, const float* __restrict__ ob,
            float* __restrict__ out, float* __restrict__ sums) {
    __shared__ float offs[2][18][34];
    __shared__ float so[64][33];

    int tid = threadIdx.x;
    int vb  = (blockIdx.x & 7) * 256 + (blockIdx.x >> 3);   // XCD-contig
    int p0  = vb * 32;
    int b   = p0 >> 14;
    int hw0 = p0 & (HW - 1);
    int y   = hw0 >> 7;
    int x0  = hw0 & 127;
    int wave = tid >> 6, lane = tid & 63;
    int mi = lane & 15, quad = lane >> 4;
    int ks = wave >> 1;
    int m0 = (wave & 1) << 4;
    int xcol = x0 + m0 + mi;
    int koff = ks * 32 + quad * 8;
    const u16* xb = xh + (size_t)b * HW * 64;
    const bf16x8* WO = (const bf16x8*)wto;
    const bf16x8* WD = (const bf16x8*)wtd;

    // ---- phase 1: offset conv partial (this ks half), loads upfront ----
    int4 av[9];
#pragma unroll
    for (int tap = 0; tap < 9; ++tap) {
        int yy = y + tap / 3 - 1;
        int xx = xcol + tap % 3 - 1;
        int yc = min(max(yy, 0), 127), xc = min(max(xx, 0), 127);
        int4 a = *(const int4*)(xb + ((yc << 7) + xc) * 64 + koff);
        if (!(((unsigned)yy < 128u) && ((unsigned)xx < 128u)))
            a = make_int4(0, 0, 0, 0);
        av[tap] = a;
    }
    f32x4 oa0 = {0.f, 0.f, 0.f, 0.f}, oa1 = {0.f, 0.f, 0.f, 0.f};
#pragma unroll
    for (int tap = 0; tap < 9; ++tap) {
        bf16x8 af = __builtin_bit_cast(bf16x8, av[tap]);
        oa0 = MFMA(af, WO[((tap * 4 + ks * 2 + 0) << 6) + lane], oa0, 0, 0, 0);
        oa1 = MFMA(af, WO[((tap * 4 + ks * 2 + 1) << 6) + lane], oa1, 0, 0, 0);
    }
    {   // C layout: col = lane&15 = n, row = quad*4+r = px-in-wave-tile
        float bias0 = (ks == 0) ? ob[mi] : 0.f;
#pragma unroll
        for (int r = 0; r < 4; ++r)
            offs[ks][mi][m0 + quad * 4 + r] = oa0[r] + bias0;
        if (mi < 2) {
            float bias1 = (ks == 0) ? ob[16 + mi] : 0.f;
#pragma unroll
            for (int r = 0; r < 4; ++r)
                offs[ks][16 + mi][m0 + quad * 4 + r] = oa1[r] + bias1;
        }
    }
    __syncthreads();

    // ---- phase 2: deformable conv (this ks half), depth-2 pipeline ----
    int pxl = m0 + mi;
    float offv[18];
#pragma unroll
    for (int m = 0; m < 18; ++m)
        offv[m] = offs[0][m][pxl] + offs[1][m][pxl];

    float fy = (float)y, fx = (float)xcol;
    // reference semantics: per-corner float-coord validity, clamped gather
    auto coords = [&](int tap, float& w00, float& w01, float& w10, float& w11,
                      int& o00, int& o01, int& o10, int& o11) {
        float py  = offv[2 * tap]     + fy + (float)(tap / 3 - 1);
        float pf  = offv[2 * tap + 1] + fx + (float)(tap % 3 - 1);
        float y0f = floorf(py), x0f = floorf(pf);
        float wy  = py - y0f,   wx  = pf - x0f;
        int   iy0 = (int)y0f,   ix0 = (int)x0f;
        float vy0 = (y0f >=  0.f && y0f <= 127.f) ? 1.f : 0.f;
        float vy1 = (y0f >= -1.f && y0f <= 126.f) ? 1.f : 0.f;
        float vx0 = (x0f >=  0.f && x0f <= 127.f) ? 1.f : 0.f;
        float vx1 = (x0f >= -1.f && x0f <= 126.f) ? 1.f : 0.f;
        int cy0 = min(max(iy0, 0), 127), cy1 = min(max(iy0 + 1, 0), 127);
        int cx0 = min(max(ix0, 0), 127), cx1 = min(max(ix0 + 1, 0), 127);
        w00 = (1.f - wy) * (1.f - wx) * vy0 * vx0;
        w01 = (1.f - wy) * wx * vy0 * vx1;
        w10 = wy * (1.f - wx) * vy1 * vx0;
        w11 = wy * wx * vy1 * vx1;
        o00 = ((cy0 << 7) + cx0) * 64 + koff;
        o01 = ((cy0 << 7) + cx1) * 64 + koff;
        o10 = ((cy1 << 7) + cx0) * 64 + koff;
        o11 = ((cy1 << 7) + cx1) * 64 + koff;
    };

    f32x4 acc0 = {0.f,0.f,0.f,0.f}, acc1 = {0.f,0.f,0.f,0.f};
    f32x4 acc2 = {0.f,0.f,0.f,0.f}, acc3 = {0.f,0.f,0.f,0.f};

    float w00, w01, w10, w11;
    int   o00, o01, o10, o11;
    coords(0, w00, w01, w10, w11, o00, o01, o10, o11);
    int4 v00 = *(const int4*)(xb + o00);
    int4 v01 = *(const int4*)(xb + o01);
    int4 v10 = *(const int4*)(xb + o10);
    int4 v11 = *(const int4*)(xb + o11);
    bf16x8 b0 = WD[((ks * 4 + 0) << 6) + lane];
    bf16x8 b1 = WD[((ks * 4 + 1) << 6) + lane];
    bf16x8 b2 = WD[((ks * 4 + 2) << 6) + lane];
    bf16x8 b3 = WD[((ks * 4 + 3) << 6) + lane];

#pragma unroll
    for (int tap = 0; tap < 9; ++tap) {
        float nw00 = w00, nw01 = w01, nw10 = w10, nw11 = w11;
        int4 nv00 = v00, nv01 = v01, nv10 = v10, nv11 = v11;
        bf16x8 nb0 = b0, nb1 = b1, nb2 = b2, nb3 = b3;
        if (tap < 8) {
            int no00, no01, no10, no11;
            coords(tap + 1, nw00, nw01, nw10, nw11, no00, no01, no10, no11);
            nv00 = *(const int4*)(xb + no00);
            nv01 = *(const int4*)(xb + no01);
            nv10 = *(const int4*)(xb + no10);
            nv11 = *(const int4*)(xb + no11);
            nb0 = WD[(((tap + 1) * 8 + ks * 4 + 0) << 6) + lane];
            nb1 = WD[(((tap + 1) * 8 + ks * 4 + 1) << 6) + lane];
            nb2 = WD[(((tap + 1) * 8 + ks * 4 + 2) << 6) + lane];
            nb3 = WD[(((tap + 1) * 8 + ks * 4 + 3) << 6) + lane];
        }
        __builtin_amdgcn_sched_barrier(0);   // pin prefetch above compute
        bf16x8 a = comb4(v00, v01, v10, v11, w00, w01, w10, w11);
        acc0 = MFMA(a, b0, acc0, 0, 0, 0);
        acc1 = MFMA(a, b1, acc1, 0, 0, 0);
        acc2 = MFMA(a, b2, acc2, 0, 0, 0);
        acc3 = MFMA(a, b3, acc3, 0, 0, 0);
        w00 = nw00; w01 = nw01; w10 = nw10; w11 = nw11;
        v00 = nv00; v01 = nv01; v10 = nv10; v11 = nv11;
        b0 = nb0; b1 = nb1; b2 = nb2; b3 = nb3;
    }

    // ---- epilogue: combine ks halves in LDS, store, BN partials ----
    if (ks == 1) {
#pragma unroll
        for (int r = 0; r < 4; ++r) {
            so[ 0 + mi][m0 + quad * 4 + r] = acc0[r];
            so[16 + mi][m0 + quad * 4 + r] = acc1[r];
            so[32 + mi][m0 + quad * 4 + r] = acc2[r];
            so[48 + mi][m0 + quad * 4 + r] = acc3[r];
        }
    }
    __syncthreads();
    if (ks == 0) {
#pragma unroll
        for (int r = 0; r < 4; ++r) {
            so[ 0 + mi][m0 + quad * 4 + r] += acc0[r];
            so[16 + mi][m0 + quad * 4 + r] += acc1[r];
            so[32 + mi][m0 + quad * 4 + r] += acc2[r];
            so[48 + mi][m0 + quad * 4 + r] += acc3[r];
        }
    }
    __syncthreads();

    int n  = tid >> 2;
    int c4 = tid & 3;
    int pl = c4 * 8;
    float s = 0.f, q = 0.f;
    float vals[8];
#pragma unroll
    for (int i = 0; i < 8; ++i) {
        float v = so[n][pl + i];
        vals[i] = v;
        s += v;
        q = fmaf(v, v, q);
    }
    float* dst = out + (size_t)(b * 64 + n) * HW + (y << 7) + x0 + pl;
    *(float4*)dst       = make_float4(vals[0], vals[1], vals[2], vals[3]);
    *(float4*)(dst + 4) = make_float4(vals[4], vals[5], vals[6], vals[7]);

    s += __shfl_xor(s, 1); s += __shfl_xor(s, 2);
    q += __shfl_xor(q, 1); q += __shfl_xor(q, 2);
    if (c4 == 0) {                          // per-XCD bin: 8x less contention
        float* sb = sums + (blockIdx.x & 7) * 128;
        atomicAdd(&sb[n], s);
        atomicAdd(&sb[64 + n], q);
    }
}

// ---------------------------------------------------------------------------
// k_bn: BN (biased var) + gamma/beta + ReLU, in place over d_out.
// sums has 8 per-XCD bins of [64 sum | 64 sumsq].
// ---------------------------------------------------------------------------
__global__ __launch_bounds__(256)
void k_bn(float* __restrict__ out, const float* __restrict__ sums,
          const float* __restrict__ gamma, const float* __restrict__ beta) {
    int i4 = blockIdx.x * 256 + threadIdx.x;
    int e  = i4 << 2;
    int o  = (e >> 14) & 63;
    float sm = 0.f, sq = 0.f;
#pragma unroll
    for (int s8 = 0; s8 < 8; ++s8) {
        sm += sums[s8 * 128 + o];
        sq += sums[s8 * 128 + 64 + o];
    }
    const float n = 65536.f;
    float mean = sm / n;
    float var  = fmaxf(sq / n - mean * mean, 0.f);
    float sc   = rsqrtf(var + 1e-5f) * gamma[o];
    float sh   = beta[o] - mean * sc;
    float4 v = *(const float4*)&out[e];
    v.x = fmaxf(fmaf(v.x, sc, sh), 0.f);
    v.y = fmaxf(fmaf(v.y, sc, sh), 0.f);
    v.z = fmaxf(fmaf(v.z, sc, sh), 0.f);
    v.w = fmaxf(fmaf(v.w, sc, sh), 0.f);
    *(float4*)&out[e] = v;
}

// ---------------------------------------------------------------------------
// Workspace layout (bytes):
//   xh   : [0, 8388608)            NHWC bf16 x
//   wtd  : [8388608, 8462336)      72 B-frags dcn weights
//   wto  : [8462336, 8499200)      36 B-frags offset weights
//   sums : [8499200, 8503296)      BN partials, 8 XCD bins (zeroed by k_pre)
// ---------------------------------------------------------------------------
extern "C" void kernel_launch(void* const* d_in, const int* in_sizes, int n_in,
                              void* d_out, int out_size, void* d_ws, size_t ws_size,
                              hipStream_t stream) {
    const float* x     = (const float*)d_in[0];
    const float* ow    = (const float*)d_in[1];
    const float* ob    = (const float*)d_in[2];
    const float* dw    = (const float*)d_in[3];
    const float* gamma = (const float*)d_in[4];
    const float* beta  = (const float*)d_in[5];
    float* out = (float*)d_out;
    char*  wsb = (char*)d_ws;
    u16*   xh   = (u16*)wsb;
    u16*   wtd  = (u16*)(wsb + 8388608);
    u16*   wto  = (u16*)(wsb + 8462336);
    float* sums = (float*)(wsb + 8499200);

    k_pre<<<540, 256, 0, stream>>>(x, dw, ow, xh, wtd, wto, sums);
    k_main<<<2048, 256, 0, stream>>>(xh, wto, wtd, ob, out, sums);
    k_bn<<<4096, 256, 0, stream>>>(out, sums, gamma, beta);
}